// Round 9
// baseline (425.421 us; speedup 1.0000x reference)
//
#include <hip/hip_runtime.h>

#define NUM_GRAPHS 1024
#define D 256

// ---------------------------------------------------------------------------
// init: zero the 1024 segment sums + 1024 counts each call.
// ---------------------------------------------------------------------------
__global__ void activs_init_kernel(float* __restrict__ sums, float* __restrict__ cnts) {
    int i = blockIdx.x * blockDim.x + threadIdx.x;
    if (i < NUM_GRAPHS) {
        sums[i] = 0.0f;
        cnts[i] = 0.0f;
    }
}

__device__ __forceinline__ float sq4(const float4 v) {
    return v.x * v.x + v.y * v.y + v.z * v.z + v.w * v.w;
}

struct Rows {
    float4 a0, a1, a2, a3;   // row r0+q
    float4 b0, b1, b2, b3;   // row r0+4+q
};

__device__ __forceinline__ void load_rows(Rows& R, const float* __restrict__ x,
                                          int r0, int q, int l) {
    const float4* srcA = (const float4*)(x + (size_t)(r0 + q) * D);
    const float4* srcB = (const float4*)(x + (size_t)(r0 + 4 + q) * D);
    R.a0 = srcA[l];
    R.a1 = srcA[l + 16];
    R.a2 = srcA[l + 32];
    R.a3 = srcA[l + 48];
    R.b0 = srcB[l];
    R.b1 = srcB[l + 16];
    R.b2 = srcB[l + 32];
    R.b3 = srcB[l + 48];
}

__device__ __forceinline__ void store_rows(const Rows& R, float* __restrict__ out,
                                           int r0, int q, int l) {
    float4* dstA = (float4*)(out + (size_t)(r0 + q) * D);
    float4* dstB = (float4*)(out + (size_t)(r0 + 4 + q) * D);
    dstA[l]      = R.a0;
    dstA[l + 16] = R.a1;
    dstA[l + 32] = R.a2;
    dstA[l + 48] = R.a3;
    dstB[l]      = R.b0;
    dstB[l + 16] = R.b1;
    dstB[l + 32] = R.b2;
    dstB[l + 48] = R.b3;
}

// ---------------------------------------------------------------------------
// PHASE B: pure streaming — NO cross-lane ops, NO divergence, NO sqrt.
// Quarter-wave rows (16 lanes per row, 8 rows/iter, depth-1 prefetch).
// Each lane keeps the sum-of-squares of its 64B slice and writes it to
// part[]: slot (row*16 + l). With q=lane>>4, l=lane&15 the two stores per
// iteration are part[r0*16 + lane] and part[r0*16 + 64 + lane] — fully
// coalesced dword stores by construction.
// ---------------------------------------------------------------------------
__global__ __launch_bounds__(256) void activs_stream_kernel(
        const float* __restrict__ x, float* __restrict__ out,
        float* __restrict__ part, int N) {
    const int lane = threadIdx.x & 63;
    const int q = lane >> 4;          // 0..3: which row of the quad
    const int l = lane & 15;          // 0..15: float4 slot within the row
    const int waveId = (blockIdx.x * blockDim.x + threadIdx.x) >> 6;
    const int totalWaves = (gridDim.x * blockDim.x) >> 6;
    const int stride = totalWaves * 8;

    const int Nq = N & ~7;            // multiple-of-8 prefix (N=1e6 -> Nq==N)

    int r = waveId * 8;
    if (r < Nq) {
        Rows cur;
        load_rows(cur, x, r, q, l);

        while (true) {
            const int rn = r + stride;
            const bool more = (rn < Nq);
            Rows nxt;
            if (more) load_rows(nxt, x, rn, q, l);   // prefetch stays in flight

            store_rows(cur, out, r, q, l);           // waits cur loads only

            const float sA = sq4(cur.a0) + sq4(cur.a1) + sq4(cur.a2) + sq4(cur.a3);
            const float sB = sq4(cur.b0) + sq4(cur.b1) + sq4(cur.b2) + sq4(cur.b3);
            float* pb = part + (size_t)r * 16;
            pb[lane] = sA;            // rows r..r+3,  slots 0..15
            pb[lane + 64] = sB;       // rows r+4..r+7, slots 0..15

            if (!more) break;
            cur = nxt;
            r = rn;
        }
    }

    // tail rows (only if N % 8 != 0; dead for N=1e6)
    if (waveId == 0) {
        for (int t = Nq; t < N; ++t) {
            const float4 v = ((const float4*)(x + (size_t)t * D))[lane];
            ((float4*)(out + (size_t)t * D))[lane] = v;
            if (lane < 16) {
                // recompute this row's slot-l partial from the 4 chunks lane
                // l owns under the quarter-wave convention
                const float4* src = (const float4*)(x + (size_t)t * D);
                float s = sq4(src[lane]) + sq4(src[lane + 16]) +
                          sq4(src[lane + 32]) + sq4(src[lane + 48]);
                part[(size_t)t * 16 + lane] = s;
            }
        }
    }
}

// ---------------------------------------------------------------------------
// PHASE C: segment reduce. Each block owns 1024 consecutive rows; each
// thread gathers 4 rows' 16 partials each (256B contiguous read), sums +
// sqrt -> 4 norms, run-length-reduces them (batch sorted) into LDS bins;
// block flushes non-empty bins with global atomics (~2 pairs/block).
// Traffic: 64MB partials + 4MB batch, coalesced.
// ---------------------------------------------------------------------------
__global__ __launch_bounds__(256) void activs_segred_kernel(
        const float* __restrict__ part, const int* __restrict__ batch,
        float* __restrict__ sums, float* __restrict__ cnts, int N) {
    __shared__ float lsum[NUM_GRAPHS];
    __shared__ float lcnt[NUM_GRAPHS];
    const int tid = threadIdx.x;

    for (int i = tid; i < NUM_GRAPHS; i += 256) {
        lsum[i] = 0.0f;
        lcnt[i] = 0.0f;
    }
    __syncthreads();

    const int base = blockIdx.x * 1024 + tid * 4;
    if (base < N) {
        // N is a multiple of 4, so base+3 < N whenever base < N
        const float4* p = (const float4*)(part + (size_t)base * 16);
        float n[4];
        #pragma unroll
        for (int k = 0; k < 4; ++k) {
            const float4 p0 = p[k * 4 + 0];
            const float4 p1 = p[k * 4 + 1];
            const float4 p2 = p[k * 4 + 2];
            const float4 p3 = p[k * 4 + 3];
            n[k] = sqrtf(p0.x + p0.y + p0.z + p0.w +
                         p1.x + p1.y + p1.z + p1.w +
                         p2.x + p2.y + p2.z + p2.w +
                         p3.x + p3.y + p3.z + p3.w);
        }
        const int4 bv = *(const int4*)(batch + base);
        const int b[4] = {bv.x, bv.y, bv.z, bv.w};
        int seg = b[0];
        float rs = n[0], rc = 1.0f;
        #pragma unroll
        for (int k = 1; k < 4; ++k) {
            if (b[k] == seg) { rs += n[k]; rc += 1.0f; }
            else {
                atomicAdd(&lsum[seg], rs);
                atomicAdd(&lcnt[seg], rc);
                seg = b[k]; rs = n[k]; rc = 1.0f;
            }
        }
        atomicAdd(&lsum[seg], rs);
        atomicAdd(&lcnt[seg], rc);
    }
    __syncthreads();

    for (int i = tid; i < NUM_GRAPHS; i += 256) {
        if (lcnt[i] != 0.0f) {
            atomicAdd(&sums[i], lsum[i]);
            atomicAdd(&cnts[i], lcnt[i]);
        }
    }
}

// ---------------------------------------------------------------------------
// FALLBACK PHASE B (R8): stream with in-kernel shuffle reduce, writes norms
// directly (4MB scratch). Used if ws is too small for the partials buffer.
// ---------------------------------------------------------------------------
__global__ __launch_bounds__(256) void activs_stream_norms_kernel(
        const float* __restrict__ x, float* __restrict__ out,
        float* __restrict__ norms, int N) {
    const int lane = threadIdx.x & 63;
    const int q = lane >> 4;
    const int l = lane & 15;
    const int waveId = (blockIdx.x * blockDim.x + threadIdx.x) >> 6;
    const int totalWaves = (gridDim.x * blockDim.x) >> 6;
    const int stride = totalWaves * 8;
    const int Nq = N & ~7;

    int r = waveId * 8;
    if (r < Nq) {
        Rows cur;
        load_rows(cur, x, r, q, l);
        while (true) {
            const int rn = r + stride;
            const bool more = (rn < Nq);
            Rows nxt;
            if (more) load_rows(nxt, x, rn, q, l);
            store_rows(cur, out, r, q, l);
            float sA = sq4(cur.a0) + sq4(cur.a1) + sq4(cur.a2) + sq4(cur.a3);
            float sB = sq4(cur.b0) + sq4(cur.b1) + sq4(cur.b2) + sq4(cur.b3);
            #pragma unroll
            for (int m = 1; m <= 8; m <<= 1) {
                sA += __shfl_xor(sA, m, 64);
                sB += __shfl_xor(sB, m, 64);
            }
            if (l == 0) {
                norms[r + q] = sqrtf(sA);
                norms[r + 4 + q] = sqrtf(sB);
            }
            if (!more) break;
            cur = nxt;
            r = rn;
        }
    }
    if (waveId == 0) {
        for (int t = Nq; t < N; ++t) {
            const float4 v = ((const float4*)(x + (size_t)t * D))[lane];
            ((float4*)(out + (size_t)t * D))[lane] = v;
            float s = sq4(v);
            #pragma unroll
            for (int m = 32; m; m >>= 1) s += __shfl_xor(s, m, 64);
            if (lane == 0) norms[t] = sqrtf(s);
        }
    }
}

// FALLBACK PHASE C (R8): segment reduce over precomputed norms.
__global__ __launch_bounds__(256) void activs_segred_norms_kernel(
        const float* __restrict__ norms, const int* __restrict__ batch,
        float* __restrict__ sums, float* __restrict__ cnts, int N) {
    __shared__ float lsum[NUM_GRAPHS];
    __shared__ float lcnt[NUM_GRAPHS];
    const int tid = threadIdx.x;

    for (int i = tid; i < NUM_GRAPHS; i += 256) {
        lsum[i] = 0.0f;
        lcnt[i] = 0.0f;
    }
    __syncthreads();

    const int base = blockIdx.x * 1024 + tid * 4;
    if (base < N) {
        const float4 nv = *(const float4*)(norms + base);
        const int4 bv = *(const int4*)(batch + base);
        const float n[4] = {nv.x, nv.y, nv.z, nv.w};
        const int b[4] = {bv.x, bv.y, bv.z, bv.w};
        int seg = b[0];
        float rs = n[0], rc = 1.0f;
        #pragma unroll
        for (int k = 1; k < 4; ++k) {
            if (b[k] == seg) { rs += n[k]; rc += 1.0f; }
            else {
                atomicAdd(&lsum[seg], rs);
                atomicAdd(&lcnt[seg], rc);
                seg = b[k]; rs = n[k]; rc = 1.0f;
            }
        }
        atomicAdd(&lsum[seg], rs);
        atomicAdd(&lcnt[seg], rc);
    }
    __syncthreads();

    for (int i = tid; i < NUM_GRAPHS; i += 256) {
        if (lcnt[i] != 0.0f) {
            atomicAdd(&sums[i], lsum[i]);
            atomicAdd(&cnts[i], lcnt[i]);
        }
    }
}

// ---------------------------------------------------------------------------
// finalize: per_graph = sum/count; mask i < bmax; mean / (bmax + 1).
// ---------------------------------------------------------------------------
__global__ __launch_bounds__(1024) void activs_finalize_kernel(
        const float* __restrict__ sums, const float* __restrict__ cnts,
        const int* __restrict__ batch, int N, float* __restrict__ out_scalar) {
    __shared__ float red[16];
    const int i = threadIdx.x;
    const int lane = i & 63;
    const int w = i >> 6;

    const float bmax = (float)batch[N - 1];

    float c = cnts[i];
    float pg = (c > 0.0f) ? (sums[i] / c) : 0.0f;
    float val = (((float)i) < bmax) ? pg : 0.0f;

    #pragma unroll
    for (int m = 32; m; m >>= 1) val += __shfl_xor(val, m, 64);
    if (lane == 0) red[w] = val;
    __syncthreads();

    if (w == 0) {
        float v = (lane < 16) ? red[lane] : 0.0f;
        #pragma unroll
        for (int m = 8; m; m >>= 1) v += __shfl_xor(v, m, 64);
        if (lane == 0) out_scalar[0] = v / (bmax + 1.0f);
    }
}

// ---------------------------------------------------------------------------
extern "C" void kernel_launch(void* const* d_in, const int* in_sizes, int n_in,
                              void* d_out, int out_size, void* d_ws, size_t ws_size,
                              hipStream_t stream) {
    const float* x = (const float*)d_in[0];
    const int* batch = (const int*)d_in[1];
    float* out = (float*)d_out;

    const int N = in_sizes[1];                 // 1,000,000 rows (D = 256)

    const size_t need_part = ((size_t)N * 16 + 2 * NUM_GRAPHS) * sizeof(float);
    const size_t need_norm = ((size_t)N + 2 * NUM_GRAPHS) * sizeof(float);

    if (ws_size >= need_part) {
        float* part = (float*)d_ws;            // [N*16]
        float* sums = part + (size_t)N * 16;   // [1024]
        float* cnts = sums + NUM_GRAPHS;       // [1024]

        hipLaunchKernelGGL(activs_init_kernel, dim3(4), dim3(256), 0, stream, sums, cnts);
        hipLaunchKernelGGL(activs_stream_kernel, dim3(2048), dim3(256), 0, stream,
                           x, out, part, N);
        hipLaunchKernelGGL(activs_segred_kernel, dim3((N + 1023) / 1024), dim3(256),
                           0, stream, part, batch, sums, cnts, N);
        hipLaunchKernelGGL(activs_finalize_kernel, dim3(1), dim3(1024), 0, stream,
                           sums, cnts, batch, N, out + (size_t)N * D);
    } else {
        float* norms = (float*)d_ws;           // [N]
        float* sums = norms + N;               // [1024]
        float* cnts = sums + NUM_GRAPHS;       // [1024]
        (void)need_norm;

        hipLaunchKernelGGL(activs_init_kernel, dim3(4), dim3(256), 0, stream, sums, cnts);
        hipLaunchKernelGGL(activs_stream_norms_kernel, dim3(2048), dim3(256), 0, stream,
                           x, out, norms, N);
        hipLaunchKernelGGL(activs_segred_norms_kernel, dim3((N + 1023) / 1024), dim3(256),
                           0, stream, norms, batch, sums, cnts, N);
        hipLaunchKernelGGL(activs_finalize_kernel, dim3(1), dim3(1024), 0, stream,
                           sums, cnts, batch, N, out + (size_t)N * D);
    }
}

// Round 10
// 403.353 us; speedup vs baseline: 1.0547x; 1.0547x over previous
//
#include <hip/hip_runtime.h>

#define NUM_GRAPHS 1024
#define D 256

// ---------------------------------------------------------------------------
// init: zero the 1024 segment sums + 1024 counts each call.
// ---------------------------------------------------------------------------
__global__ void activs_init_kernel(float* __restrict__ sums, float* __restrict__ cnts) {
    int i = blockIdx.x * blockDim.x + threadIdx.x;
    if (i < NUM_GRAPHS) {
        sums[i] = 0.0f;
        cnts[i] = 0.0f;
    }
}

__device__ __forceinline__ float sq4(const float4 v) {
    return v.x * v.x + v.y * v.y + v.z * v.z + v.w * v.w;
}

// 8 rows per wave-iteration, FULL-ROW mapping: lane owns float4 slot `lane`
// of every row; one load/store instruction = one 1KB contiguous row segment
// (m13-copy-style), vs the quarter-wave mapping's 4x256B chunks.
struct Rows8 {
    float4 v0, v1, v2, v3, v4, v5, v6, v7;
};

__device__ __forceinline__ void load8(Rows8& R, const float* __restrict__ x,
                                      int r, int lane) {
    R.v0 = ((const float4*)(x + (size_t)(r + 0) * D))[lane];
    R.v1 = ((const float4*)(x + (size_t)(r + 1) * D))[lane];
    R.v2 = ((const float4*)(x + (size_t)(r + 2) * D))[lane];
    R.v3 = ((const float4*)(x + (size_t)(r + 3) * D))[lane];
    R.v4 = ((const float4*)(x + (size_t)(r + 4) * D))[lane];
    R.v5 = ((const float4*)(x + (size_t)(r + 5) * D))[lane];
    R.v6 = ((const float4*)(x + (size_t)(r + 6) * D))[lane];
    R.v7 = ((const float4*)(x + (size_t)(r + 7) * D))[lane];
}

__device__ __forceinline__ void store8(const Rows8& R, float* __restrict__ out,
                                       int r, int lane) {
    ((float4*)(out + (size_t)(r + 0) * D))[lane] = R.v0;
    ((float4*)(out + (size_t)(r + 1) * D))[lane] = R.v1;
    ((float4*)(out + (size_t)(r + 2) * D))[lane] = R.v2;
    ((float4*)(out + (size_t)(r + 3) * D))[lane] = R.v3;
    ((float4*)(out + (size_t)(r + 4) * D))[lane] = R.v4;
    ((float4*)(out + (size_t)(r + 5) * D))[lane] = R.v5;
    ((float4*)(out + (size_t)(r + 6) * D))[lane] = R.v6;
    ((float4*)(out + (size_t)(r + 7) * D))[lane] = R.v7;
}

// ---------------------------------------------------------------------------
// PHASE B: streaming with full-row (1KB contiguous per instruction) access,
// 8 rows/iter, depth-1 prefetch. 8 full-wave butterflies produce the 8 row
// sums (uniform across the wave after reduce); predicated selects route row
// j's norm to lane j; one coalesced 8-dword store writes norms[r..r+7].
// ---------------------------------------------------------------------------
__global__ __launch_bounds__(256) void activs_stream_kernel(
        const float* __restrict__ x, float* __restrict__ out,
        float* __restrict__ norms, int N) {
    const int lane = threadIdx.x & 63;
    const int waveId = (blockIdx.x * blockDim.x + threadIdx.x) >> 6;
    const int totalWaves = (gridDim.x * blockDim.x) >> 6;
    const int stride = totalWaves * 8;

    const int Nq = N & ~7;            // multiple-of-8 prefix (N=1e6 -> Nq==N)

    int r = waveId * 8;
    if (r < Nq) {
        Rows8 cur;
        load8(cur, x, r, lane);

        while (true) {
            const int rn = r + stride;
            const bool more = (rn < Nq);
            Rows8 nxt;
            if (more) load8(nxt, x, rn, lane);   // prefetch stays in flight

            store8(cur, out, r, lane);           // waits cur loads only

            float s0 = sq4(cur.v0), s1 = sq4(cur.v1);
            float s2 = sq4(cur.v2), s3 = sq4(cur.v3);
            float s4 = sq4(cur.v4), s5 = sq4(cur.v5);
            float s6 = sq4(cur.v6), s7 = sq4(cur.v7);
            #pragma unroll
            for (int m = 1; m <= 32; m <<= 1) {
                s0 += __shfl_xor(s0, m, 64);
                s1 += __shfl_xor(s1, m, 64);
                s2 += __shfl_xor(s2, m, 64);
                s3 += __shfl_xor(s3, m, 64);
                s4 += __shfl_xor(s4, m, 64);
                s5 += __shfl_xor(s5, m, 64);
                s6 += __shfl_xor(s6, m, 64);
                s7 += __shfl_xor(s7, m, 64);
            }
            // route row j's (wave-uniform) sum to lane j, one coalesced store
            float nv = s0;
            nv = (lane == 1) ? s1 : nv;
            nv = (lane == 2) ? s2 : nv;
            nv = (lane == 3) ? s3 : nv;
            nv = (lane == 4) ? s4 : nv;
            nv = (lane == 5) ? s5 : nv;
            nv = (lane == 6) ? s6 : nv;
            nv = (lane == 7) ? s7 : nv;
            if (lane < 8) norms[r + lane] = sqrtf(nv);

            if (!more) break;
            cur = nxt;
            r = rn;
        }
    }

    // tail rows (only if N % 8 != 0; dead for N=1e6)
    if (waveId == 0) {
        for (int t = Nq; t < N; ++t) {
            const float4 v = ((const float4*)(x + (size_t)t * D))[lane];
            ((float4*)(out + (size_t)t * D))[lane] = v;
            float s = sq4(v);
            #pragma unroll
            for (int m = 32; m; m >>= 1) s += __shfl_xor(s, m, 64);
            if (lane == 0) norms[t] = sqrtf(s);
        }
    }
}

// ---------------------------------------------------------------------------
// PHASE C: segment reduce over norms (R8-proven). Each block owns 1024
// consecutive rows; each thread run-length-reduces 4 consecutive rows
// (batch sorted) into LDS bins; block flushes non-empty bins with global
// atomics (~2 pairs/block). Traffic: 4MB norms + 4MB batch, coalesced.
// ---------------------------------------------------------------------------
__global__ __launch_bounds__(256) void activs_segred_kernel(
        const float* __restrict__ norms, const int* __restrict__ batch,
        float* __restrict__ sums, float* __restrict__ cnts, int N) {
    __shared__ float lsum[NUM_GRAPHS];
    __shared__ float lcnt[NUM_GRAPHS];
    const int tid = threadIdx.x;

    for (int i = tid; i < NUM_GRAPHS; i += 256) {
        lsum[i] = 0.0f;
        lcnt[i] = 0.0f;
    }
    __syncthreads();

    const int base = blockIdx.x * 1024 + tid * 4;
    if (base < N) {
        // N is a multiple of 4, so base+3 < N whenever base < N
        const float4 nv = *(const float4*)(norms + base);
        const int4 bv = *(const int4*)(batch + base);
        const float n[4] = {nv.x, nv.y, nv.z, nv.w};
        const int b[4] = {bv.x, bv.y, bv.z, bv.w};
        int seg = b[0];
        float rs = n[0], rc = 1.0f;
        #pragma unroll
        for (int k = 1; k < 4; ++k) {
            if (b[k] == seg) { rs += n[k]; rc += 1.0f; }
            else {
                atomicAdd(&lsum[seg], rs);
                atomicAdd(&lcnt[seg], rc);
                seg = b[k]; rs = n[k]; rc = 1.0f;
            }
        }
        atomicAdd(&lsum[seg], rs);
        atomicAdd(&lcnt[seg], rc);
    }
    __syncthreads();

    for (int i = tid; i < NUM_GRAPHS; i += 256) {
        if (lcnt[i] != 0.0f) {
            atomicAdd(&sums[i], lsum[i]);
            atomicAdd(&cnts[i], lcnt[i]);
        }
    }
}

// ---------------------------------------------------------------------------
// FALLBACK (R6 fused): streaming + in-loop segment atomics; used only if ws
// can't hold the norms buffer.
// ---------------------------------------------------------------------------
__global__ __launch_bounds__(256) void activs_fused_kernel(
        const float* __restrict__ x, const int* __restrict__ batch,
        float* __restrict__ out, float* __restrict__ sums,
        float* __restrict__ cnts, int N) {
    const int lane = threadIdx.x & 63;
    const int waveId = (blockIdx.x * blockDim.x + threadIdx.x) >> 6;
    const int totalWaves = (gridDim.x * blockDim.x) >> 6;
    const int stride = totalWaves * 8;
    const int Nq = N & ~7;

    int r = waveId * 8;
    if (r < Nq) {
        Rows8 cur;
        load8(cur, x, r, lane);
        int4 w0 = ((const int4*)(batch + r))[0];
        int4 w1 = ((const int4*)(batch + r))[1];

        while (true) {
            const int rn = r + stride;
            const bool more = (rn < Nq);
            Rows8 nxt;
            int4 nw0, nw1;
            if (more) {
                load8(nxt, x, rn, lane);
                nw0 = ((const int4*)(batch + rn))[0];
                nw1 = ((const int4*)(batch + rn))[1];
            }
            store8(cur, out, r, lane);

            float s0 = sq4(cur.v0), s1 = sq4(cur.v1);
            float s2 = sq4(cur.v2), s3 = sq4(cur.v3);
            float s4 = sq4(cur.v4), s5 = sq4(cur.v5);
            float s6 = sq4(cur.v6), s7 = sq4(cur.v7);
            #pragma unroll
            for (int m = 1; m <= 32; m <<= 1) {
                s0 += __shfl_xor(s0, m, 64);
                s1 += __shfl_xor(s1, m, 64);
                s2 += __shfl_xor(s2, m, 64);
                s3 += __shfl_xor(s3, m, 64);
                s4 += __shfl_xor(s4, m, 64);
                s5 += __shfl_xor(s5, m, 64);
                s6 += __shfl_xor(s6, m, 64);
                s7 += __shfl_xor(s7, m, 64);
            }

            if (lane == 0) {
                const float n[8] = {sqrtf(s0), sqrtf(s1), sqrtf(s2), sqrtf(s3),
                                    sqrtf(s4), sqrtf(s5), sqrtf(s6), sqrtf(s7)};
                const int b[8] = {w0.x, w0.y, w0.z, w0.w, w1.x, w1.y, w1.z, w1.w};
                int seg = b[0];
                float rs = n[0], rc = 1.0f;
                #pragma unroll
                for (int k = 1; k < 8; ++k) {
                    if (b[k] == seg) { rs += n[k]; rc += 1.0f; }
                    else {
                        atomicAdd(&sums[seg], rs);
                        atomicAdd(&cnts[seg], rc);
                        seg = b[k]; rs = n[k]; rc = 1.0f;
                    }
                }
                atomicAdd(&sums[seg], rs);
                atomicAdd(&cnts[seg], rc);
            }

            if (!more) break;
            cur = nxt; w0 = nw0; w1 = nw1; r = rn;
        }
    }
    if (waveId == 0) {
        for (int t = Nq; t < N; ++t) {
            const float4 v = ((const float4*)(x + (size_t)t * D))[lane];
            ((float4*)(out + (size_t)t * D))[lane] = v;
            float s = sq4(v);
            #pragma unroll
            for (int m = 32; m; m >>= 1) s += __shfl_xor(s, m, 64);
            if (lane == 0) {
                atomicAdd(&sums[batch[t]], sqrtf(s));
                atomicAdd(&cnts[batch[t]], 1.0f);
            }
        }
    }
}

// ---------------------------------------------------------------------------
// finalize: per_graph = sum/count; mask i < bmax; mean / (bmax + 1).
// ---------------------------------------------------------------------------
__global__ __launch_bounds__(1024) void activs_finalize_kernel(
        const float* __restrict__ sums, const float* __restrict__ cnts,
        const int* __restrict__ batch, int N, float* __restrict__ out_scalar) {
    __shared__ float red[16];
    const int i = threadIdx.x;
    const int lane = i & 63;
    const int w = i >> 6;

    const float bmax = (float)batch[N - 1];

    float c = cnts[i];
    float pg = (c > 0.0f) ? (sums[i] / c) : 0.0f;
    float val = (((float)i) < bmax) ? pg : 0.0f;

    #pragma unroll
    for (int m = 32; m; m >>= 1) val += __shfl_xor(val, m, 64);
    if (lane == 0) red[w] = val;
    __syncthreads();

    if (w == 0) {
        float v = (lane < 16) ? red[lane] : 0.0f;
        #pragma unroll
        for (int m = 8; m; m >>= 1) v += __shfl_xor(v, m, 64);
        if (lane == 0) out_scalar[0] = v / (bmax + 1.0f);
    }
}

// ---------------------------------------------------------------------------
extern "C" void kernel_launch(void* const* d_in, const int* in_sizes, int n_in,
                              void* d_out, int out_size, void* d_ws, size_t ws_size,
                              hipStream_t stream) {
    const float* x = (const float*)d_in[0];
    const int* batch = (const int*)d_in[1];
    float* out = (float*)d_out;

    const int N = in_sizes[1];                 // 1,000,000 rows (D = 256)

    const size_t need_norm = ((size_t)N + 2 * NUM_GRAPHS) * sizeof(float);

    if (ws_size >= need_norm) {
        float* norms = (float*)d_ws;           // [N]
        float* sums = norms + N;               // [1024]
        float* cnts = sums + NUM_GRAPHS;       // [1024]

        hipLaunchKernelGGL(activs_init_kernel, dim3(4), dim3(256), 0, stream, sums, cnts);
        hipLaunchKernelGGL(activs_stream_kernel, dim3(2048), dim3(256), 0, stream,
                           x, out, norms, N);
        hipLaunchKernelGGL(activs_segred_kernel, dim3((N + 1023) / 1024), dim3(256),
                           0, stream, norms, batch, sums, cnts, N);
        hipLaunchKernelGGL(activs_finalize_kernel, dim3(1), dim3(1024), 0, stream,
                           sums, cnts, batch, N, out + (size_t)N * D);
    } else {
        float* sums = (float*)d_ws;            // [1024]
        float* cnts = sums + NUM_GRAPHS;       // [1024]

        hipLaunchKernelGGL(activs_init_kernel, dim3(4), dim3(256), 0, stream, sums, cnts);
        hipLaunchKernelGGL(activs_fused_kernel, dim3(2048), dim3(256), 0, stream,
                           x, batch, out, sums, cnts, N);
        hipLaunchKernelGGL(activs_finalize_kernel, dim3(1), dim3(1024), 0, stream,
                           sums, cnts, batch, N, out + (size_t)N * D);
    }
}